// Round 1
// 179.098 us; speedup vs baseline: 1.0240x; 1.0240x over previous
//
#include <hip/hip_runtime.h>
#include <math.h>

#define NEGV  -10000000000.0f
#define LOG2E 1.44269504088896340736f
#define LN2F  0.69314718055994530942f

typedef float f4 __attribute__((ext_vector_type(4)));

constexpr int CS    = 32;          // diagonal steps per chunk (was 16)
constexpr int ROWS  = 96;          // staged rows per wave-chunk (need 95)
constexpr int WL    = 33;          // LDS words per row (32 data + 1 pad)
constexpr int CHW   = ROWS * WL;   // words per chunk buffer (3168)
constexpr int KCMAX = 32;          // chunk count for N=M=512 (T=1023)
constexpr int SIT   = 48;          // staging iterations (2 rows x 32 cols each)

// One block per batch. Thread j owns DP column j+1. Waves free-run (NO global
// barrier): wave w publishes its lane-63 chunk boundary (32 values) into a
// full-history LDS buffer and release-stores a per-chunk flag; wave w+1
// acquire-spins only while its lane 0 is still active. Theta LDS is
// wave-private, SINGLE-buffered (safe: all reads of chunk c are consumed in
// registers before the chunk-(c+1) writes issue; the end-of-chunk lgkmcnt(0)
// drain orders writes against the next chunk's reads). CS=16 -> 32 halves the
// number of handoff/staging overheads paid along the critical path.
__global__ __launch_bounds__(512, 2) void nw_kernel(
    const float* __restrict__ theta, const float* __restrict__ A,
    float* __restrict__ out, int N, int M)
{
    __shared__ float thS[8 * CHW];             // 101,376 B (wave-private halves)
    __shared__ float bndD[9 * KCMAX * CS];     //  36,864 B full boundary history
    __shared__ int   flg[9 * KCMAX];           //   1,152 B

    const int tid = threadIdx.x;
    const int w   = tid >> 6;
    const int l   = tid & 63;
    const int j   = tid;                 // owns column j+1
    const int b   = blockIdx.x;
    const int NW  = blockDim.x >> 6;

    // zero flags; the ONLY block-wide barrier in the kernel
    for (int i = tid; i < 9 * KCMAX; i += blockDim.x) flg[i] = 0;
    __syncthreads();

    const float a2 = A[b] * LOG2E;
    const float* __restrict__ thb = theta + (size_t)b * N * M;
    const int NM = N * M;

    const int T  = N + M - 1;
    const int KC = (T + CS - 1) / CS;
    const int wstart = 64 * w;
    const int wend   = 64 * w + 63 + N - 1;
    const int ca = wstart / CS;                     // first chunk this wave computes
    const int cb = min(KC - 1, wend / CS);          // last chunk

    // staging lane constants: 48 iterations x (2 rows x 32 cols)
    const int srow = l >> 5;                        // 0..1
    const int sq   = l & 31;                        // 0..31
    const int lanebase = srow * (M - 1) + 64 * w + 63 + sq;
    const int wrbase   = w * CHW + srow * WL + sq;
    const int rdbase   = w * CHW + (63 - l) * WL;

    auto stage_load = [&](int cn, float* stg) {
        const int rb = CS * cn - 64 * w - 63;
        if (rb >= 0 && rb + (ROWS - 1) <= N - 1) {
            const float* p = thb + (size_t)rb * M;   // uniform base + lane offset
            #pragma unroll
            for (int it = 0; it < SIT; ++it) { stg[it] = p[lanebase]; p += 2 * (M - 1); }
        } else {
            const int rbM = rb * M;                  // edge: flat clamp
            #pragma unroll
            for (int it = 0; it < SIT; ++it) {
                int off = rbM + lanebase + it * 2 * (M - 1);
                off = min(max(off, 0), NM - 1);
                stg[it] = thb[off];
            }
        }
    };
    auto stage_write = [&](const float* stg) {
        #pragma unroll
        for (int it = 0; it < SIT; ++it) thS[wrbase + it * 2 * WL] = stg[it] * LOG2E;
    };
    auto wait_flag = [&](int idx) {
        if (__atomic_load_n(&flg[idx], __ATOMIC_ACQUIRE) == 0) {
            do { __builtin_amdgcn_s_sleep(1); }
            while (__atomic_load_n(&flg[idx], __ATOMIC_ACQUIRE) == 0);
        }
    };

    float v_prev = NEGV;                    // V2[i][j+1] running value
    float v_diag = (j == 0) ? 0.0f : NEGV;  // V2[0][0] = 0 seeds thread 0
    float bcarry = NEGV;                    // neighbor boundary, step CS*c - 1

    // prologue: stage chunk ca into LDS (self-consumed; intra-wave ordering)
    {
        float s0[SIT];
        stage_load(ca, s0);
        stage_write(s0);
        __asm__ volatile("s_waitcnt lgkmcnt(0)" ::: "memory");
    }
    if (w > 0) {                            // bcarry for first chunk is real data
        wait_flag(w * KCMAX + (ca - 1));
        bcarry = bndD[(w * KCMAX + ca - 1) * CS + (CS - 1)];
    }

    float stg[SIT];
    bool have = (ca + 1 <= cb);
    if (have) stage_load(ca + 1, stg);

    for (int c = ca; c <= cb; ++c) {
        // first 8 theta reads early (latency overlaps flag spin; the acquire's
        // lgkmcnt(0) drain then only covers 8 outstanding reads, not 32)
        float th[CS];
        #pragma unroll
        for (int k = 0; k < 8; ++k) th[k] = thS[rdbase + k * (WL + 1)];

        // neighbor boundary — only while this wave's lane 0 is still active
        const bool need_bv = (w > 0) && (CS * c <= 64 * w + N - 1);
        float bv[CS];
        if (need_bv) {
            wait_flag(w * KCMAX + c);
            const f4* src = (const f4*)&bndD[(w * KCMAX + c) * CS];
            #pragma unroll
            for (int q = 0; q < CS / 4; ++q) {
                f4 t = src[q];
                bv[4*q+0] = t.x; bv[4*q+1] = t.y; bv[4*q+2] = t.z; bv[4*q+3] = t.w;
            }
        } else {
            #pragma unroll
            for (int k = 0; k < CS; ++k) bv[k] = NEGV;
        }

        // remaining theta reads; latency hides under the first cells' compute
        #pragma unroll
        for (int k = 8; k < CS; ++k) th[k] = thS[rdbase + k * (WL + 1)];

        float res[CS];
        const bool full = (CS * c >= 64 * w + 63) &&
                          (CS * c + CS - 1 <= 64 * w + N - 1);
        if (full) {
            #pragma unroll
            for (int k = 0; k < CS; ++k) {
                float bk = (k == 0) ? bcarry : bv[k - 1];
                float vl = __int_as_float(__builtin_amdgcn_update_dpp(
                    __float_as_int(bk), __float_as_int(v_prev),
                    0x138 /* wave_shr:1 */, 0xF, 0xF, false));
                float x = a2 + v_prev;
                float z = a2 + vl;
                float m = fmaxf(fmaxf(x, v_diag), z);
                float s = __builtin_amdgcn_exp2f(x - m)
                        + __builtin_amdgcn_exp2f(v_diag - m)
                        + __builtin_amdgcn_exp2f(z - m);
                float v = th[k] + m + __builtin_amdgcn_logf(s);
                res[k] = v;
                v_diag = vl;
                v_prev = v;
            }
        } else {
            const int tmj = CS * c - j;
            #pragma unroll
            for (int k = 0; k < CS; ++k) {
                float bk = (k == 0) ? bcarry : bv[k - 1];
                float vl = __int_as_float(__builtin_amdgcn_update_dpp(
                    __float_as_int(bk), __float_as_int(v_prev),
                    0x138, 0xF, 0xF, false));
                float x = a2 + v_prev;
                float z = a2 + vl;
                float m = fmaxf(fmaxf(x, v_diag), z);
                float s = __builtin_amdgcn_exp2f(x - m)
                        + __builtin_amdgcn_exp2f(v_diag - m)
                        + __builtin_amdgcn_exp2f(z - m);
                float v = th[k] + m + __builtin_amdgcn_logf(s);
                int dt = tmj + k;            // t - j; active iff 0 <= dt < N
                float vn = ((unsigned)dt < (unsigned)N) ? v
                                                        : (dt < 0 ? NEGV : v_prev);
                res[k] = vn;
                v_diag = vl;
                v_prev = vn;
            }
        }

        // publish boundary to next wave, then release the flag
        if (w < NW - 1 && l == 63) {
            f4* dst = (f4*)&bndD[((w + 1) * KCMAX + c) * CS];
            #pragma unroll
            for (int q = 0; q < CS / 4; ++q)
                dst[q] = (f4){res[4*q+0], res[4*q+1], res[4*q+2], res[4*q+3]};
            __atomic_store_n(&flg[(w + 1) * KCMAX + c], 1, __ATOMIC_RELEASE);
        }
        bcarry = bv[CS - 1];

        // write staged theta for c+1 (overwrites this chunk's window — safe:
        // all reads above are already consumed), issue loads for c+2
        if (have) stage_write(stg);
        have = (c + 2 <= cb);
        if (have) stage_load(c + 2, stg);
        __asm__ volatile("s_waitcnt lgkmcnt(0)" ::: "memory");
    }

    if (j == M - 1) out[b] = v_prev * LN2F;   // V[N][M], back to ln domain
}

extern "C" void kernel_launch(void* const* d_in, const int* in_sizes, int n_in,
                              void* d_out, int out_size, void* d_ws, size_t ws_size,
                              hipStream_t stream) {
    const float* theta = (const float*)d_in[0];
    const float* A     = (const float*)d_in[1];
    float* out = (float*)d_out;

    const int B  = in_sizes[1];
    const int NM = in_sizes[0] / B;
    int N = 1;
    while (N * N < NM) N <<= 1;   // 512x512 expected
    const int M = NM / N;

    hipLaunchKernelGGL(nw_kernel, dim3(B), dim3(M), 0, stream,
                       theta, A, out, N, M);
}

// Round 2
// 178.674 us; speedup vs baseline: 1.0264x; 1.0024x over previous
//
#include <hip/hip_runtime.h>
#include <math.h>

#define NEGV  -10000000000.0f
#define LOG2E 1.44269504088896340736f
#define LN2F  0.69314718055994530942f

typedef float f4 __attribute__((ext_vector_type(4)));

constexpr int CS    = 32;          // diagonal steps per chunk
constexpr int ROWS  = 96;          // staged rows per wave-chunk (need 95)
constexpr int WL    = 33;          // LDS words per row (32 data + 1 pad)
constexpr int CHW   = ROWS * WL;   // words per chunk buffer (3168)
constexpr int KCMAX = 32;          // chunk count for N=M=512 (T=1023)
constexpr int SIT   = 48;          // staging iterations (2 rows x 32 cols each)

// Pair-state formulation: each DP value is carried as (m, s) with v = m+log2(s).
// Recurrence: m' = max3(a2+mp, md, a2+ml); mn = th + m';
//             sn = sp*exp2(a2+mp-m') + sd*exp2(md-m') + sl*exp2(a2+ml-m').
// The m-chain (add->max3->add) has NO transcendentals -> per-cell dependent
// latency drops from ~127 cyc to ~16; the s-chain (3 exp2 + fma) trails at a
// constant one-cell lag. Exponent-folding renorm once per chunk keeps s in
// [0.5, 2^52) exactly. Boundary handoff stays collapsed scalars (s=1), so the
// LDS layout / flags / staging pipeline are identical to the previous version.
__global__ __launch_bounds__(512, 2) void nw_kernel(
    const float* __restrict__ theta, const float* __restrict__ A,
    float* __restrict__ out, int N, int M)
{
    __shared__ float thS[8 * CHW];             // 101,376 B (wave-private halves)
    __shared__ float bndD[9 * KCMAX * CS];     //  36,864 B full boundary history
    __shared__ int   flg[9 * KCMAX];           //   1,152 B

    const int tid = threadIdx.x;
    const int w   = tid >> 6;
    const int l   = tid & 63;
    const int j   = tid;                 // owns column j+1
    const int b   = blockIdx.x;
    const int NW  = blockDim.x >> 6;

    // zero flags; the ONLY block-wide barrier in the kernel
    for (int i = tid; i < 9 * KCMAX; i += blockDim.x) flg[i] = 0;
    __syncthreads();

    const float a2 = A[b] * LOG2E;
    const float* __restrict__ thb = theta + (size_t)b * N * M;
    const int NM = N * M;

    const int T  = N + M - 1;
    const int KC = (T + CS - 1) / CS;
    const int wstart = 64 * w;
    const int wend   = 64 * w + 63 + N - 1;
    const int ca = wstart / CS;                     // first chunk this wave computes
    const int cb = min(KC - 1, wend / CS);          // last chunk

    // staging lane constants: 48 iterations x (2 rows x 32 cols)
    const int srow = l >> 5;                        // 0..1
    const int sq   = l & 31;                        // 0..31
    const int lanebase = srow * (M - 1) + 64 * w + 63 + sq;
    const int wrbase   = w * CHW + srow * WL + sq;
    const int rdbase   = w * CHW + (63 - l) * WL;

    auto stage_load = [&](int cn, float* stg) {
        const int rb = CS * cn - 64 * w - 63;
        if (rb >= 0 && rb + (ROWS - 1) <= N - 1) {
            const float* p = thb + (size_t)rb * M;   // uniform base + lane offset
            #pragma unroll
            for (int it = 0; it < SIT; ++it) { stg[it] = p[lanebase]; p += 2 * (M - 1); }
        } else {
            const int rbM = rb * M;                  // edge: flat clamp
            #pragma unroll
            for (int it = 0; it < SIT; ++it) {
                int off = rbM + lanebase + it * 2 * (M - 1);
                off = min(max(off, 0), NM - 1);
                stg[it] = thb[off];
            }
        }
    };
    auto stage_write = [&](const float* stg) {
        #pragma unroll
        for (int it = 0; it < SIT; ++it) thS[wrbase + it * 2 * WL] = stg[it] * LOG2E;
    };
    auto wait_flag = [&](int idx) {
        if (__atomic_load_n(&flg[idx], __ATOMIC_ACQUIRE) == 0) {
            do { __builtin_amdgcn_s_sleep(1); }
            while (__atomic_load_n(&flg[idx], __ATOMIC_ACQUIRE) == 0);
        }
    };

    // pair state: value = m + log2(s)
    float mp = NEGV, sp = 1.0f;                    // own previous value
    float md = (j == 0) ? 0.0f : NEGV, sd = 1.0f;  // diag (left neighbor, -2 steps)
    float bcarry = NEGV;                           // boundary value, step CS*c - 1

    // prologue: stage chunk ca into LDS (self-consumed; intra-wave ordering)
    {
        float s0[SIT];
        stage_load(ca, s0);
        stage_write(s0);
        __asm__ volatile("s_waitcnt lgkmcnt(0)" ::: "memory");
    }
    if (w > 0) {                            // bcarry for first chunk is real data
        wait_flag(w * KCMAX + (ca - 1));
        bcarry = bndD[(w * KCMAX + ca - 1) * CS + (CS - 1)];
    }

    float stg[SIT];
    bool have = (ca + 1 <= cb);
    if (have) stage_load(ca + 1, stg);

    for (int c = ca; c <= cb; ++c) {
        // first 8 theta reads early (latency overlaps flag spin)
        float th[CS];
        #pragma unroll
        for (int k = 0; k < 8; ++k) th[k] = thS[rdbase + k * (WL + 1)];

        // neighbor boundary — only while this wave's lane 0 is still active
        const bool need_bv = (w > 0) && (CS * c <= 64 * w + N - 1);
        float bv[CS];
        if (need_bv) {
            wait_flag(w * KCMAX + c);
            const f4* src = (const f4*)&bndD[(w * KCMAX + c) * CS];
            #pragma unroll
            for (int q = 0; q < CS / 4; ++q) {
                f4 t = src[q];
                bv[4*q+0] = t.x; bv[4*q+1] = t.y; bv[4*q+2] = t.z; bv[4*q+3] = t.w;
            }
        } else {
            #pragma unroll
            for (int k = 0; k < CS; ++k) bv[k] = NEGV;
        }

        // remaining theta reads; latency hides under the first cells' compute
        #pragma unroll
        for (int k = 8; k < CS; ++k) th[k] = thS[rdbase + k * (WL + 1)];

        float res[CS];
        const bool full = (CS * c >= 64 * w + 63) &&
                          (CS * c + CS - 1 <= 64 * w + N - 1);
        if (full) {
            #pragma unroll
            for (int k = 0; k < CS; ++k) {
                float bm = (k == 0) ? bcarry : bv[k - 1];
                float ml = __int_as_float(__builtin_amdgcn_update_dpp(
                    __float_as_int(bm), __float_as_int(mp),
                    0x138 /* wave_shr:1 */, 0xF, 0xF, false));
                float sl = __int_as_float(__builtin_amdgcn_update_dpp(
                    0x3f800000 /* 1.0f */, __float_as_int(sp),
                    0x138, 0xF, 0xF, false));
                float u  = a2 + mp;
                float ul = a2 + ml;
                float mx = fmaxf(fmaxf(u, md), ul);       // v_max3_f32
                float e1 = __builtin_amdgcn_exp2f(u  - mx);
                float e2 = __builtin_amdgcn_exp2f(md - mx);
                float e3 = __builtin_amdgcn_exp2f(ul - mx);
                float sn = fmaf(sl, e3, fmaf(sd, e2, sp * e1));
                float mn = th[k] + mx;
                res[k] = mn + __builtin_amdgcn_logf(sn);  // collapse (off-chain)
                md = ml; sd = sl;
                mp = mn; sp = sn;
            }
        } else {
            const int tmj = CS * c - j;
            #pragma unroll
            for (int k = 0; k < CS; ++k) {
                float bm = (k == 0) ? bcarry : bv[k - 1];
                float ml = __int_as_float(__builtin_amdgcn_update_dpp(
                    __float_as_int(bm), __float_as_int(mp),
                    0x138, 0xF, 0xF, false));
                float sl = __int_as_float(__builtin_amdgcn_update_dpp(
                    0x3f800000, __float_as_int(sp),
                    0x138, 0xF, 0xF, false));
                float u  = a2 + mp;
                float ul = a2 + ml;
                float mx = fmaxf(fmaxf(u, md), ul);
                float e1 = __builtin_amdgcn_exp2f(u  - mx);
                float e2 = __builtin_amdgcn_exp2f(md - mx);
                float e3 = __builtin_amdgcn_exp2f(ul - mx);
                float sn = fmaf(sl, e3, fmaf(sd, e2, sp * e1));
                float mn = th[k] + mx;
                int dt = tmj + k;            // t - j; active iff 0 <= dt < N
                bool act = (unsigned)dt < (unsigned)N;
                float mq = act ? mn : (dt < 0 ? NEGV : mp);
                float sq2 = act ? sn : (dt < 0 ? 1.0f : sp);
                res[k] = mq + __builtin_amdgcn_logf(sq2);
                md = ml; sd = sl;
                mp = mq; sp = sq2;
            }
        }

        // publish boundary to next wave, then release the flag
        if (w < NW - 1 && l == 63) {
            f4* dst = (f4*)&bndD[((w + 1) * KCMAX + c) * CS];
            #pragma unroll
            for (int q = 0; q < CS / 4; ++q)
                dst[q] = (f4){res[4*q+0], res[4*q+1], res[4*q+2], res[4*q+3]};
            __atomic_store_n(&flg[(w + 1) * KCMAX + c], 1, __ATOMIC_RELEASE);
        }
        bcarry = bv[CS - 1];

        // exact renorm: fold exponent of s into m (bounds s without rounding)
        {
            int bs = __float_as_int(sp);
            int ex = ((bs >> 23) & 0xff) - 127;
            sp = __int_as_float(bs - (ex << 23));
            mp += (float)ex;
            int bd = __float_as_int(sd);
            int ed = ((bd >> 23) & 0xff) - 127;
            sd = __int_as_float(bd - (ed << 23));
            md += (float)ed;
        }

        // write staged theta for c+1, issue loads for c+2
        if (have) stage_write(stg);
        have = (c + 2 <= cb);
        if (have) stage_load(c + 2, stg);
        __asm__ volatile("s_waitcnt lgkmcnt(0)" ::: "memory");
    }

    if (j == M - 1)
        out[b] = (mp + __builtin_amdgcn_logf(sp)) * LN2F;  // back to ln domain
}

extern "C" void kernel_launch(void* const* d_in, const int* in_sizes, int n_in,
                              void* d_out, int out_size, void* d_ws, size_t ws_size,
                              hipStream_t stream) {
    const float* theta = (const float*)d_in[0];
    const float* A     = (const float*)d_in[1];
    float* out = (float*)d_out;

    const int B  = in_sizes[1];
    const int NM = in_sizes[0] / B;
    int N = 1;
    while (N * N < NM) N <<= 1;   // 512x512 expected
    const int M = NM / N;

    hipLaunchKernelGGL(nw_kernel, dim3(B), dim3(M), 0, stream,
                       theta, A, out, N, M);
}